// Round 14
// baseline (60.218 us; speedup 1.0000x reference)
//
#include <hip/hip_runtime.h>

#define MDIM 512
#define LDIM 31
#define WDIM 542            // MDIM + LDIM - 1
#define ROW_IN (MDIM*LDIM)  // 15872 floats per (b,r) row
#define NROWS 2048          // B * MDIM
#define BLK_C 192           // c-values per chunk (3*192 = 576 >= 542)
#define NCH 3
#define NR 226              // staged rows m in [c0-32, c0+193]
#define SX4 1752            // ceil(NR*31/4)
#define NLD 7               // ceil(SX4/256)
#define NSLOT 8
#define HTILE (256*LDIM)    // 7936 floats: half-row output tile

// Barrier that drains LDS ops only — global loads to REGISTERS stay in flight.
__device__ __forceinline__ void bar_lgkm() {
    asm volatile("s_waitcnt lgkmcnt(0)\n\ts_barrier" ::: "memory");
}

__device__ __forceinline__ float wave_max(float v) {
    #pragma unroll
    for (int off = 32; off > 0; off >>= 1)
        v = fmaxf(v, __shfl_xor(v, off));
    return v;
}

__device__ __forceinline__ float sigmoid10(float h) {
    return 1.0f / (1.0f + __expf(-10.0f * h));
}

__global__ void kInit(unsigned int* g) {
    const int t = threadIdx.x;
    if (t < NSLOT * 32) g[t] = 0u;
}

// g[c] = sum_i Hs[c-i]*x[c-i][i], i=0..30. s_hs/s_x zero outside valid m.
// All LDS reads use POSITIVE compile-time offsets (<=255 floats) from a few
// rebased base pointers, so SILoadStoreOptimizer can fold offsets and merge
// pairs into ds_read2_b32 (halves LDS instruction count; no per-tap v_add).
// Min cr = 30 (c=-2) keeps every rebased offset >= 0.
__device__ __forceinline__ float compute_g(int c, int rlo,
                                           const float* __restrict__ s_hs,
                                           const float* __restrict__ s_x) {
    const int cr = c - rlo;                        // in [30, 225]
    const float* hb = s_hs + (cr - 30);            // hb[30-i] = Hs[c-i], off 0..30
    const float* xb = s_x + cr * LDIM;             // tap i at xb - 30i
    const float* b0 = xb - 210;                    // i=0..7:   off = 210-30i
    const float* b1 = xb - 450;                    // i=8..15:  off = 450-30i
    const float* b2 = xb - 690;                    // i=16..23: off = 690-30i
    const float* b3 = xb - 900;                    // i=24..30: off = 900-30i

    float xr[31], hr[31];
    #pragma unroll
    for (int i = 0; i < 8; ++i)   xr[i] = b0[210 - 30 * i];
    #pragma unroll
    for (int i = 8; i < 16; ++i)  xr[i] = b1[450 - 30 * i];
    #pragma unroll
    for (int i = 16; i < 24; ++i) xr[i] = b2[690 - 30 * i];
    #pragma unroll
    for (int i = 24; i < 31; ++i) xr[i] = b3[900 - 30 * i];
    #pragma unroll
    for (int i = 0; i < 31; ++i)  hr[i] = hb[30 - i];

    float a0 = 0.f, a1 = 0.f, a2 = 0.f, a3 = 0.f;
    #pragma unroll
    for (int i = 0; i < 28; i += 4) {
        a0 = fmaf(hr[i],     xr[i],     a0);
        a1 = fmaf(hr[i + 1], xr[i + 1], a1);
        a2 = fmaf(hr[i + 2], xr[i + 2], a2);
        a3 = fmaf(hr[i + 3], xr[i + 3], a3);
    }
    a0 = fmaf(hr[28], xr[28], a0);
    a1 = fmaf(hr[29], xr[29], a1);
    a2 = fmaf(hr[30], xr[30], a2);
    return (a0 + a1) + (a2 + a3);
}

// s_g[gt] = g(c0-2+gt); ys = (c - (c0-1)).
__device__ __forceinline__ float yval(int ys, int c, int rlo,
                                      const float* __restrict__ s_hs,
                                      const float* __restrict__ s_x,
                                      const float* __restrict__ s_g) {
    const int rb = c - 31 - rlo;
    const int rc = c + 1 - rlo;
    const float B = s_hs[rb] * s_x[rb * LDIM + 30];
    const float C = s_hs[rc] * s_x[rc * LDIM];
    return 0.5f * s_g[ys + 1] + 0.25f * (s_g[ys] - B) + 0.25f * (s_g[ys + 2] - C);
}

// One block per row; 3 chunk-tasks with cross-chunk register prefetch.
__global__ __launch_bounds__(256, 4) void kMainP(const float* __restrict__ inp,
                                                 const float* __restrict__ H,
                                                 float* __restrict__ y_out,
                                                 unsigned int* __restrict__ slots) {
    __shared__ __align__(16) float s_x[SX4 * 4];   // 28032 B
    __shared__ float s_hs[NR];
    __shared__ float s_g[BLK_C + 4];
    __shared__ float s_y[BLK_C + 2];
    __shared__ float s_red[8];

    const int br = blockIdx.x;
    const int r  = br & (MDIM - 1);
    const int t  = threadIdx.x;
    const float4* row4 = (const float4*)(inp + (size_t)br * ROW_IN);

    float lmaxy = 0.f, lmaxz = 0.f;
    float4 v[NLD];

    {
        const int g4start = ((0 - 32) * LDIM) >> 2;        // -248
        const int lo4 = 248;
        #pragma unroll
        for (int j = 0; j < NLD; ++j) {
            const int idx = t + 256 * j;
            v[j] = make_float4(0.f, 0.f, 0.f, 0.f);
            if (idx >= lo4 && idx < SX4) v[j] = row4[g4start + idx];
        }
        #pragma unroll
        for (int j = 0; j < NLD; ++j) {
            const int idx = t + 256 * j;
            if (idx < SX4) ((float4*)s_x)[idx] = v[j];
        }
    }

    for (int ch = 0; ch < NCH; ++ch) {
        const int c0  = ch * BLK_C;
        const int rlo = c0 - 32;

        if (t < NR) {
            const int m = rlo + t;
            s_hs[t] = (m >= 0 && m < MDIM)
                      ? sigmoid10(H[(size_t)r * MDIM + m]) : 0.f;
        }

        if (ch + 1 < NCH) {
            const int nrlo = (ch + 1) * BLK_C - 32;
            const int g4start = (nrlo * LDIM) >> 2;
            int hi4 = ROW_IN / 4 - g4start; if (hi4 > SX4) hi4 = SX4;
            #pragma unroll
            for (int j = 0; j < NLD; ++j) {
                const int idx = t + 256 * j;
                v[j] = make_float4(0.f, 0.f, 0.f, 0.f);
                if (idx < hi4) v[j] = row4[g4start + idx];
            }
        }

        bar_lgkm();

        {
            const int c = c0 - 2 + t;
            if (t < BLK_C + 4 && c <= WDIM + 1)
                s_g[t] = compute_g(c, rlo, s_hs, s_x);
        }
        bar_lgkm();

        {
            const int c = c0 + t;
            if (t <= BLK_C && c <= WDIM) {
                const float yv = yval(t + 1, c, rlo, s_hs, s_x, s_g);
                s_y[t + 1] = yv;
                if (t < BLK_C && c < WDIM) {
                    y_out[(size_t)br * WDIM + c] = yv;
                    lmaxy = fmaxf(lmaxy, yv);
                }
            }
            if (t == 0) s_y[0] = yval(0, c0 - 1, rlo, s_hs, s_x, s_g);
        }
        bar_lgkm();

        if (t < BLK_C && c0 + t < WDIM) {
            const float yl = s_y[t], ym = s_y[t + 1], yr = s_y[t + 2];
            const float wf  = 0.25f * yl + 0.5f * ym + 0.25f * yr;
            const float w0  = 0.5f * ym + 0.25f * yr;
            const float w30 = 0.25f * yl + 0.5f * ym;
            float hm = s_hs[t + 3];
            #pragma unroll
            for (int j = 4; j <= 31; ++j) hm = fmaxf(hm, s_hs[t + j]);
            lmaxz = fmaxf(lmaxz,
                          fmaxf(wf * hm, fmaxf(w0 * s_hs[t + 32], w30 * s_hs[t + 2])));
        }

        bar_lgkm();

        if (ch + 1 < NCH) {
            #pragma unroll
            for (int j = 0; j < NLD; ++j) {
                const int idx = t + 256 * j;
                if (idx < SX4) ((float4*)s_x)[idx] = v[j];
            }
        }
    }

    const float wy = wave_max(lmaxy);
    const float wz = wave_max(lmaxz);
    const int wv = t >> 6, ln = t & 63;
    if (ln == 0) { s_red[wv] = wy; s_red[4 + wv] = wz; }
    __syncthreads();
    if (t == 0) {
        const float my = fmaxf(fmaxf(s_red[0], s_red[1]), fmaxf(s_red[2], s_red[3]));
        const float mz = fmaxf(fmaxf(s_red[4], s_red[5]), fmaxf(s_red[6], s_red[7]));
        const int slot = br & (NSLOT - 1);
        atomicMax(&slots[slot * 32],      __float_as_uint(my));
        atomicMax(&slots[slot * 32 + 16], __float_as_uint(mz));
    }
}

// One block per row. m-row-per-thread blur in registers, outputs staged
// through a stride-31 LDS tile, coalesced float4 copy-out. 2 half-row passes.
__global__ __launch_bounds__(256, 4) void kB2(const float* __restrict__ H,
                                              float* __restrict__ out,
                                              const unsigned int* __restrict__ slots) {
    __shared__ float s_yp[WDIM + 2];                 // yp[j] = y[j-1]; pads 0
    __shared__ float s_hs[MDIM];
    __shared__ __align__(16) float s_t[HTILE];       // 31744 B

    const int br = blockIdx.x;
    const int b  = br >> 9;
    const int r  = br & (MDIM - 1);
    const int t  = threadIdx.x;

    float* xout  = out;                                   // [NROWS][ROW_IN]
    float* yout  = out + (size_t)NROWS * ROW_IN;          // [NROWS][WDIM]
    float* hsout = yout + (size_t)NROWS * WDIM;           // [MDIM*MDIM]

    #pragma unroll
    for (int j = 0; j < 3; ++j) {
        const int idx = t + 256 * j;
        if (idx < WDIM + 2)
            s_yp[idx] = (idx >= 1 && idx <= WDIM)
                        ? yout[(size_t)br * WDIM + idx - 1] : 0.f;
    }
    const float* hrow = H + (size_t)r * MDIM;
    s_hs[t]       = sigmoid10(hrow[t]);
    s_hs[t + 256] = sigmoid10(hrow[t + 256]);

    float my = 0.f, mz = 0.f;
    #pragma unroll
    for (int s = 0; s < NSLOT; ++s) {
        my = fmaxf(my, __uint_as_float(slots[s * 32]));
        mz = fmaxf(mz, __uint_as_float(slots[s * 32 + 16]));
    }
    const float inv_my = 1.0f / my;
    const float inv_mz = 1.0f / mz;
    __syncthreads();

    #pragma unroll
    for (int j = 0; j < 3; ++j) {
        const int c = t + 256 * j;
        if (c < WDIM) yout[(size_t)br * WDIM + c] = s_yp[c + 1] * inv_my;
    }
    if (b == 0) {
        hsout[(size_t)r * MDIM + t]       = s_hs[t];
        hsout[(size_t)r * MDIM + t + 256] = s_hs[t + 256];
    }

    #pragma unroll
    for (int pass = 0; pass < 2; ++pass) {
        const int m = pass * 256 + t;
        const float hscale = s_hs[m] * inv_mz;

        float a[32];
        #pragma unroll
        for (int k = 1; k <= 31; ++k) a[k] = s_yp[m + k];  // y[m .. m+30]

        // o[0]  = 0.5*y[m] + 0.25*y[m+1] -> a[0]
        // o[l]  = 0.25*a[l] + 0.5*a[l+1] + 0.25*a[l+2] (ascending, hazard-free)
        a[0] = 0.5f * a[1] + 0.25f * a[2];
        #pragma unroll
        for (int l = 1; l <= 29; ++l)
            a[l] = 0.25f * a[l] + 0.5f * a[l + 1] + 0.25f * a[l + 2];
        a[30] = 0.25f * a[30] + 0.5f * a[31];

        float* dst = s_t + t * LDIM;
        #pragma unroll
        for (int l = 0; l < LDIM; ++l) dst[l] = a[l] * hscale;

        __syncthreads();

        float4* xr4 = (float4*)(xout + (size_t)br * ROW_IN + pass * HTILE);
        const float4* st4 = (const float4*)s_t;
        #pragma unroll
        for (int j = 0; j < 8; ++j) {
            const int w = t + 256 * j;
            if (w < HTILE / 4) xr4[w] = st4[w];
        }

        __syncthreads();
    }
}

extern "C" void kernel_launch(void* const* d_in, const int* in_sizes, int n_in,
                              void* d_out, int out_size, void* d_ws, size_t ws_size,
                              hipStream_t stream) {
    const float* inp = (const float*)d_in[0];   // (4,512,512,31) f32
    const float* H   = (const float*)d_in[1];   // (1,512,512,1,1) f32
    float* out = (float*)d_out;
    unsigned int* slots = (unsigned int*)d_ws;  // 8 cacheline-padded max slots
    float* yraw = out + (size_t)NROWS * ROW_IN; // y slot: raw from kMainP, normalized by kB2

    hipLaunchKernelGGL(kInit, dim3(1), dim3(256), 0, stream, slots);
    hipLaunchKernelGGL(kMainP, dim3(NROWS), dim3(256), 0, stream, inp, H, yraw, slots);
    hipLaunchKernelGGL(kB2, dim3(NROWS), dim3(256), 0, stream, H, out, slots);
}

// Round 15
// 58.884 us; speedup vs baseline: 1.0227x; 1.0227x over previous
//
#include <hip/hip_runtime.h>

#define MDIM 512
#define LDIM 31
#define WDIM 542            // MDIM + LDIM - 1
#define ROW_IN (MDIM*LDIM)  // 15872 floats per (b,r) row
#define NROWS 2048          // B * MDIM
#define BLK_C 192           // c-values per chunk (3*192 = 576 >= 542)
#define NCH 3
#define NR 226              // staged rows m in [c0-32, c0+193]
#define SX4 1752            // ceil(NR*31/4)
#define NLD 7               // ceil(SX4/256)
#define NSLOT 8
#define HTILE (256*LDIM)    // 7936 floats: half-row output tile

// Barrier that drains LDS ops only — global loads to REGISTERS stay in flight.
__device__ __forceinline__ void bar_lgkm() {
    asm volatile("s_waitcnt lgkmcnt(0)\n\ts_barrier" ::: "memory");
}

__device__ __forceinline__ float wave_max(float v) {
    #pragma unroll
    for (int off = 32; off > 0; off >>= 1)
        v = fmaxf(v, __shfl_xor(v, off));
    return v;
}

__device__ __forceinline__ float sigmoid10(float h) {
    return 1.0f / (1.0f + __expf(-10.0f * h));
}

__global__ void kInit(unsigned int* g) {
    const int t = threadIdx.x;
    if (t < NSLOT * 32) g[t] = 0u;
}

// g[c] = sum_i Hs[c-i]*x[c-i][i], i=0..30. s_hs/s_x zero outside valid m.
// (R14's rebased-positive-offset form, kept as latest green.)
__device__ __forceinline__ float compute_g(int c, int rlo,
                                           const float* __restrict__ s_hs,
                                           const float* __restrict__ s_x) {
    const int cr = c - rlo;                        // in [30, 225]
    const float* hb = s_hs + (cr - 30);            // hb[30-i] = Hs[c-i]
    const float* xb = s_x + cr * LDIM;             // tap i at xb - 30i
    const float* b0 = xb - 210;
    const float* b1 = xb - 450;
    const float* b2 = xb - 690;
    const float* b3 = xb - 900;

    float xr[31], hr[31];
    #pragma unroll
    for (int i = 0; i < 8; ++i)   xr[i] = b0[210 - 30 * i];
    #pragma unroll
    for (int i = 8; i < 16; ++i)  xr[i] = b1[450 - 30 * i];
    #pragma unroll
    for (int i = 16; i < 24; ++i) xr[i] = b2[690 - 30 * i];
    #pragma unroll
    for (int i = 24; i < 31; ++i) xr[i] = b3[900 - 30 * i];
    #pragma unroll
    for (int i = 0; i < 31; ++i)  hr[i] = hb[30 - i];

    float a0 = 0.f, a1 = 0.f, a2 = 0.f, a3 = 0.f;
    #pragma unroll
    for (int i = 0; i < 28; i += 4) {
        a0 = fmaf(hr[i],     xr[i],     a0);
        a1 = fmaf(hr[i + 1], xr[i + 1], a1);
        a2 = fmaf(hr[i + 2], xr[i + 2], a2);
        a3 = fmaf(hr[i + 3], xr[i + 3], a3);
    }
    a0 = fmaf(hr[28], xr[28], a0);
    a1 = fmaf(hr[29], xr[29], a1);
    a2 = fmaf(hr[30], xr[30], a2);
    return (a0 + a1) + (a2 + a3);
}

// s_g[gt] = g(c0-2+gt); ys = (c - (c0-1)).
__device__ __forceinline__ float yval(int ys, int c, int rlo,
                                      const float* __restrict__ s_hs,
                                      const float* __restrict__ s_x,
                                      const float* __restrict__ s_g) {
    const int rb = c - 31 - rlo;
    const int rc = c + 1 - rlo;
    const float B = s_hs[rb] * s_x[rb * LDIM + 30];
    const float C = s_hs[rc] * s_x[rc * LDIM];
    return 0.5f * s_g[ys + 1] + 0.25f * (s_g[ys] - B) + 0.25f * (s_g[ys + 2] - C);
}

// One block per row; 3 chunk-tasks. 3 barriers/chunk: the s_x commit and the
// next chunk's Hs staging (double-buffered) overlap with the Z-max phase.
__global__ __launch_bounds__(256, 4) void kMainP(const float* __restrict__ inp,
                                                 const float* __restrict__ H,
                                                 float* __restrict__ y_out,
                                                 unsigned int* __restrict__ slots) {
    __shared__ __align__(16) float s_x[SX4 * 4];   // 28032 B
    __shared__ float s_hs[2][NR];                  // 1808 B (double-buffered)
    __shared__ float s_g[BLK_C + 4];
    __shared__ float s_y[BLK_C + 2];
    __shared__ float s_red[8];

    const int br = blockIdx.x;
    const int r  = br & (MDIM - 1);
    const int t  = threadIdx.x;
    const float4* row4 = (const float4*)(inp + (size_t)br * ROW_IN);
    const float* hrow  = H + (size_t)r * MDIM;

    float lmaxy = 0.f, lmaxz = 0.f;
    float4 v[NLD];

    // ---- prologue: stage chunk-0 window + chunk-0 Hs (buf 0) ----
    {
        const int g4start = ((0 - 32) * LDIM) >> 2;        // -248
        const int lo4 = 248;
        #pragma unroll
        for (int j = 0; j < NLD; ++j) {
            const int idx = t + 256 * j;
            v[j] = make_float4(0.f, 0.f, 0.f, 0.f);
            if (idx >= lo4 && idx < SX4) v[j] = row4[g4start + idx];
        }
        #pragma unroll
        for (int j = 0; j < NLD; ++j) {
            const int idx = t + 256 * j;
            if (idx < SX4) ((float4*)s_x)[idx] = v[j];
        }
        if (t < NR) {
            const int m = -32 + t;
            s_hs[0][t] = (m >= 0) ? sigmoid10(hrow[m]) : 0.f;   // m < NR-32 < MDIM
        }
    }
    bar_lgkm();

    #pragma unroll
    for (int ch = 0; ch < NCH; ++ch) {
        const int c0  = ch * BLK_C;
        const int rlo = c0 - 32;
        const int cur = ch & 1;
        const float* hs = s_hs[cur];

        // issue NEXT chunk's global loads into registers (in flight across bars)
        if (ch + 1 < NCH) {
            const int nrlo = (ch + 1) * BLK_C - 32;
            const int g4start = (nrlo * LDIM) >> 2;
            int hi4 = ROW_IN / 4 - g4start; if (hi4 > SX4) hi4 = SX4;
            #pragma unroll
            for (int j = 0; j < NLD; ++j) {
                const int idx = t + 256 * j;
                v[j] = make_float4(0.f, 0.f, 0.f, 0.f);
                if (idx < hi4) v[j] = row4[g4start + idx];
            }
        }

        // ---- g phase ----
        {
            const int c = c0 - 2 + t;
            if (t < BLK_C + 4 && c <= WDIM + 1)
                s_g[t] = compute_g(c, rlo, hs, s_x);
        }
        bar_lgkm();

        // ---- y phase ----
        {
            const int c = c0 + t;
            if (t <= BLK_C && c <= WDIM) {
                const float yv = yval(t + 1, c, rlo, hs, s_x, s_g);
                s_y[t + 1] = yv;
                if (t < BLK_C && c < WDIM) {
                    y_out[(size_t)br * WDIM + c] = yv;
                    lmaxy = fmaxf(lmaxy, yv);
                }
            }
            if (t == 0) s_y[0] = yval(0, c0 - 1, rlo, hs, s_x, s_g);
        }
        bar_lgkm();

        // ---- overlap slot: Z (reads s_y, hs[cur]) || commit s_x || stage hs[cur^1] ----
        if (ch + 1 < NCH) {
            #pragma unroll
            for (int j = 0; j < NLD; ++j) {
                const int idx = t + 256 * j;
                if (idx < SX4) ((float4*)s_x)[idx] = v[j];
            }
            if (t < NR) {
                const int m = (ch + 1) * BLK_C - 32 + t;
                s_hs[cur ^ 1][t] = (m >= 0 && m < MDIM) ? sigmoid10(hrow[m]) : 0.f;
            }
        }

        if (t < BLK_C && c0 + t < WDIM) {
            const float yl = s_y[t], ym = s_y[t + 1], yr = s_y[t + 2];
            const float wf  = 0.25f * yl + 0.5f * ym + 0.25f * yr;  // l in [1,29]
            const float w0  = 0.5f * ym + 0.25f * yr;               // l = 0
            const float w30 = 0.25f * yl + 0.5f * ym;               // l = 30
            float hm = hs[t + 3];
            #pragma unroll
            for (int j = 4; j <= 31; ++j) hm = fmaxf(hm, hs[t + j]);
            lmaxz = fmaxf(lmaxz,
                          fmaxf(wf * hm, fmaxf(w0 * hs[t + 32], w30 * hs[t + 2])));
        }

        if (ch + 1 < NCH) bar_lgkm();   // commit + hs-stage visible for next g
    }

    // ---- block reduce + hashed-slot atomics ----
    const float wy = wave_max(lmaxy);
    const float wz = wave_max(lmaxz);
    const int wv = t >> 6, ln = t & 63;
    if (ln == 0) { s_red[wv] = wy; s_red[4 + wv] = wz; }
    __syncthreads();
    if (t == 0) {
        const float my = fmaxf(fmaxf(s_red[0], s_red[1]), fmaxf(s_red[2], s_red[3]));
        const float mz = fmaxf(fmaxf(s_red[4], s_red[5]), fmaxf(s_red[6], s_red[7]));
        const int slot = br & (NSLOT - 1);
        atomicMax(&slots[slot * 32],      __float_as_uint(my));
        atomicMax(&slots[slot * 32 + 16], __float_as_uint(mz));
    }
}

// One block per row. m-row-per-thread blur in registers, outputs staged
// through a stride-31 LDS tile, coalesced float4 copy-out. (Green since R13.)
__global__ __launch_bounds__(256, 4) void kB2(const float* __restrict__ H,
                                              float* __restrict__ out,
                                              const unsigned int* __restrict__ slots) {
    __shared__ float s_yp[WDIM + 2];                 // yp[j] = y[j-1]; pads 0
    __shared__ float s_hs[MDIM];
    __shared__ __align__(16) float s_t[HTILE];       // 31744 B

    const int br = blockIdx.x;
    const int b  = br >> 9;
    const int r  = br & (MDIM - 1);
    const int t  = threadIdx.x;

    float* xout  = out;                                   // [NROWS][ROW_IN]
    float* yout  = out + (size_t)NROWS * ROW_IN;          // [NROWS][WDIM]
    float* hsout = yout + (size_t)NROWS * WDIM;           // [MDIM*MDIM]

    #pragma unroll
    for (int j = 0; j < 3; ++j) {
        const int idx = t + 256 * j;
        if (idx < WDIM + 2)
            s_yp[idx] = (idx >= 1 && idx <= WDIM)
                        ? yout[(size_t)br * WDIM + idx - 1] : 0.f;
    }
    const float* hrow = H + (size_t)r * MDIM;
    s_hs[t]       = sigmoid10(hrow[t]);
    s_hs[t + 256] = sigmoid10(hrow[t + 256]);

    float my = 0.f, mz = 0.f;
    #pragma unroll
    for (int s = 0; s < NSLOT; ++s) {
        my = fmaxf(my, __uint_as_float(slots[s * 32]));
        mz = fmaxf(mz, __uint_as_float(slots[s * 32 + 16]));
    }
    const float inv_my = 1.0f / my;
    const float inv_mz = 1.0f / mz;
    __syncthreads();

    #pragma unroll
    for (int j = 0; j < 3; ++j) {
        const int c = t + 256 * j;
        if (c < WDIM) yout[(size_t)br * WDIM + c] = s_yp[c + 1] * inv_my;
    }
    if (b == 0) {
        hsout[(size_t)r * MDIM + t]       = s_hs[t];
        hsout[(size_t)r * MDIM + t + 256] = s_hs[t + 256];
    }

    #pragma unroll
    for (int pass = 0; pass < 2; ++pass) {
        const int m = pass * 256 + t;
        const float hscale = s_hs[m] * inv_mz;

        float a[32];
        #pragma unroll
        for (int k = 1; k <= 31; ++k) a[k] = s_yp[m + k];

        a[0] = 0.5f * a[1] + 0.25f * a[2];
        #pragma unroll
        for (int l = 1; l <= 29; ++l)
            a[l] = 0.25f * a[l] + 0.5f * a[l + 1] + 0.25f * a[l + 2];
        a[30] = 0.25f * a[30] + 0.5f * a[31];

        float* dst = s_t + t * LDIM;
        #pragma unroll
        for (int l = 0; l < LDIM; ++l) dst[l] = a[l] * hscale;

        __syncthreads();

        float4* xr4 = (float4*)(xout + (size_t)br * ROW_IN + pass * HTILE);
        const float4* st4 = (const float4*)s_t;
        #pragma unroll
        for (int j = 0; j < 8; ++j) {
            const int w = t + 256 * j;
            if (w < HTILE / 4) xr4[w] = st4[w];
        }

        __syncthreads();
    }
}

extern "C" void kernel_launch(void* const* d_in, const int* in_sizes, int n_in,
                              void* d_out, int out_size, void* d_ws, size_t ws_size,
                              hipStream_t stream) {
    const float* inp = (const float*)d_in[0];   // (4,512,512,31) f32
    const float* H   = (const float*)d_in[1];   // (1,512,512,1,1) f32
    float* out = (float*)d_out;
    unsigned int* slots = (unsigned int*)d_ws;  // 8 cacheline-padded max slots
    float* yraw = out + (size_t)NROWS * ROW_IN; // y slot: raw from kMainP, normalized by kB2

    hipLaunchKernelGGL(kInit, dim3(1), dim3(256), 0, stream, slots);
    hipLaunchKernelGGL(kMainP, dim3(NROWS), dim3(256), 0, stream, inp, H, yraw, slots);
    hipLaunchKernelGGL(kB2, dim3(NROWS), dim3(256), 0, stream, H, out, slots);
}